// Round 6
// baseline (389.712 us; speedup 1.0000x reference)
//
#include <hip/hip_runtime.h>
#include <cstdint>

#define D_MODEL 1024
#define D_INNER 2048
#define LSEQ    4096
#define BATCH   2
#define M_ROWS  (BATCH * LSEQ)   // 8192
#define CHUNK   128
#define NCHUNK  (LSEQ / CHUNK)   // 32

typedef unsigned short u16;
typedef __bf16 bf16x8 __attribute__((ext_vector_type(8)));
typedef float f32x16 __attribute__((ext_vector_type(16)));
typedef u16 u16x4 __attribute__((ext_vector_type(4)));

__device__ __forceinline__ u16 f2bf(float f) {
  union { float f; unsigned u; } x; x.f = f;
  unsigned u = x.u;
  unsigned r = (u + 0x7FFFu + ((u >> 16) & 1u)) >> 16;
  return (u16)r;
}
__device__ __forceinline__ float bf2f(u16 h) {
  union { unsigned u; float f; } x; x.u = ((unsigned)h) << 16;
  return x.f;
}
__device__ __forceinline__ float sigmoidf_(float v) { return 1.0f / (1.0f + expf(-v)); }
__device__ __forceinline__ float siluf_(float v)    { return v / (1.0f + expf(-v)); }

__device__ __forceinline__ void gl_lds16(const void* g, void* l) {
  __builtin_amdgcn_global_load_lds(
      (const __attribute__((address_space(1))) void*)g,
      (__attribute__((address_space(3))) void*)l, 16, 0, 0);
}

#define SBAR()   asm volatile("s_barrier" ::: "memory")
#define WAITV0() asm volatile("s_waitcnt vmcnt(0)" ::: "memory")

// ---------------- cast fp32 -> bf16 (vectorized) ----------------
__global__ void __launch_bounds__(256)
cast_bf16_kernel(const float* __restrict__ in, u16* __restrict__ out, int n4) {
  int i = blockIdx.x * 256 + threadIdx.x;
  if (i < n4) {
    float4 v = ((const float4*)in)[i];
    u16x4 o;
    o.x = f2bf(v.x); o.y = f2bf(v.y); o.z = f2bf(v.z); o.w = f2bf(v.w);
    ((u16x4*)out)[i] = o;
  }
}

// ---------------- LayerNorm -> bf16 ----------------
__global__ void __launch_bounds__(256)
ln_kernel(const float* __restrict__ x, const float* __restrict__ w,
          const float* __restrict__ b, u16* __restrict__ xn) {
  const int row = blockIdx.x;
  const int t = threadIdx.x;
  const float4 v = ((const float4*)(x + (size_t)row * D_MODEL))[t];
  float s  = v.x + v.y + v.z + v.w;
  float ss = v.x * v.x + v.y * v.y + v.z * v.z + v.w * v.w;
#pragma unroll
  for (int o = 32; o > 0; o >>= 1) {
    s  += __shfl_xor(s, o);
    ss += __shfl_xor(ss, o);
  }
  __shared__ float red[8];
  const int wid = t >> 6, lane = t & 63;
  if (lane == 0) { red[wid] = s; red[4 + wid] = ss; }
  __syncthreads();
  s  = red[0] + red[1] + red[2] + red[3];
  ss = red[4] + red[5] + red[6] + red[7];
  const float mu  = s * (1.0f / D_MODEL);
  const float var = ss * (1.0f / D_MODEL) - mu * mu;
  const float rs  = rsqrtf(var + 1e-5f);
  const float4 wv = ((const float4*)w)[t];
  const float4 bv = ((const float4*)b)[t];
  u16x4 o4;
  o4.x = f2bf((v.x - mu) * rs * wv.x + bv.x);
  o4.y = f2bf((v.y - mu) * rs * wv.y + bv.y);
  o4.z = f2bf((v.z - mu) * rs * wv.z + bv.z);
  o4.w = f2bf((v.w - mu) * rs * wv.w + bv.w);
  ((u16x4*)(xn + (size_t)row * D_MODEL))[t] = o4;
}

// ======== "fat wave" 256xBN GEMM: 4 waves, wave tile 128x(BN/2), 32x32x16 ====
// One wave/SIMD; 16 independent acc tiles per k-step give ~512 cyc of MFMA
// pipe backlog that hides lgkm waits, barrier, and vm residual. BK=64 dbuf;
// 1 barrier + 1 vmcnt(0) per tile (loads issued >=1.5 k-tiles before wait).
// LDS rows 128B with (row&7)<<4 XOR swizzle (0-conflict, verified R2-R4);
// staged via pre-swizzled per-lane global source, linear LDS dest.
template<int EPI, int BN>
__global__ void __launch_bounds__(256, 1)
gemmW(const u16* __restrict__ A, const u16* __restrict__ Bm,
      int M, int N, int K,
      const float* __restrict__ ef, float* __restrict__ of,
      u16* __restrict__ ob0, u16* __restrict__ ob1) {
  constexpr int NF     = BN / 64;      // B frags per wave per k-step (32 cols each)
  constexpr int NBS    = BN / 32;      // B stage instrs per wave per tile
  constexpr int BBYTES = BN * 128;     // one B K-tile in LDS
  __shared__ __align__(1024) char lds[65536 + 2 * BBYTES];
  const int tid  = threadIdx.x;
  const int wid  = tid >> 6, lane = tid & 63;
  const int nbx  = N / BN;
  const int nwg  = nbx * (M >> 8);
  const int bid  = blockIdx.x;
  const int cpx  = nwg >> 3;                      // nwg % 8 == 0 for all our shapes
  const int swzb = (bid & 7) * cpx + (bid >> 3);  // XCD-aware swizzle
  const int bx   = swzb % nbx, by = swzb / nbx;
  const size_t m0 = (size_t)by << 8;
  const size_t n0 = (size_t)bx * BN;
  const int widm = wid >> 1, widn = wid & 1;      // 2x2 wave grid
  const size_t rb  = (size_t)K * 2;
  const size_t rj8 = 8 * rb;

  // ---- staging addressing ----
  const int sr = lane >> 3;                       // slab-local row 0..7
  const int ss = ((lane & 7) ^ sr) << 4;          // pre-swizzled 16B slot
  const char* gAs = (const char*)A  + (m0 + (size_t)(wid * 64 + sr)) * rb + ss;
  const char* gBs = (const char*)Bm + (n0 + (size_t)(wid * (BN / 4) + sr)) * rb + ss;
  const int sAo = wid * 8192;                     // wave A slab (64 rows)
  const int sBo = wid * (BN * 32);                // wave B slab (BN/4 rows)

  // ---- fragment read addressing (32x32x16: row=lane&31, k=8*(lane>>5)+e) ----
  const int l31  = lane & 31;
  const int hi16 = (lane >> 5) << 4;
  const int sx   = (lane & 7) << 4;
  const int arow = (widm * 128 + l31) * 128;
  const int brow = (widn * (BN / 2) + l31) * 128;

  f32x16 acc[4][NF] = {};

  auto LDA = [&](bf16x8 (&d)[4], const char* Ab, int kk) {
    const int ko = ((kk * 32) | hi16) ^ sx;
#pragma unroll
    for (int mi = 0; mi < 4; ++mi)
      d[mi] = *(const bf16x8*)(Ab + arow + mi * 4096 + ko);
  };
  auto LDB = [&](bf16x8 (&d)[NF], const char* Bb, int kk) {
    const int ko = ((kk * 32) | hi16) ^ sx;
#pragma unroll
    for (int ni = 0; ni < NF; ++ni)
      d[ni] = *(const bf16x8*)(Bb + brow + ni * 4096 + ko);
  };
  auto MM = [&](bf16x8 (&a)[4], bf16x8 (&b)[NF]) {
#pragma unroll
    for (int mi = 0; mi < 4; ++mi)
#pragma unroll
      for (int ni = 0; ni < NF; ++ni)
        acc[mi][ni] = __builtin_amdgcn_mfma_f32_32x32x16_bf16(a[mi], b[ni], acc[mi][ni], 0, 0, 0);
  };

  const int nk = K >> 6;

  // ---- prologue: stage tile 0 into buffer 0 ----
#pragma unroll
  for (int j = 0; j < 8; ++j)   gl_lds16(gAs + (size_t)j * rj8, lds + sAo + j * 1024);
#pragma unroll
  for (int j = 0; j < NBS; ++j) gl_lds16(gBs + (size_t)j * rj8, lds + 65536 + sBo + j * 1024);
  WAITV0();
  SBAR();

  bf16x8 aE[4], bE[NF], aO[4], bO[NF];
  LDA(aE, lds, 0); LDB(bE, lds + 65536, 0);

  size_t kb = 128;
  for (int t = 0; t < nk; ++t) {
    const int cur = t & 1;
    const char* Ac = lds + cur * 32768;
    const char* Bc = lds + 65536 + cur * BBYTES;
    char* An = lds + (cur ^ 1) * 32768;
    char* Bn = lds + 65536 + (cur ^ 1) * BBYTES;
    const bool pf = (t + 1 < nk);

    // kk0: read kk1 frags; stage part of t+1; MFMA kk0
    LDA(aO, Ac, 1); LDB(bO, Bc, 1);
    if (pf) {
      gl_lds16(gAs + kb,            An + sAo);
      gl_lds16(gAs + kb + rj8,      An + sAo + 1024);
      gl_lds16(gAs + kb + 2 * rj8,  An + sAo + 2048);
      gl_lds16(gBs + kb,            Bn + sBo);
      gl_lds16(gBs + kb + rj8,      Bn + sBo + 1024);
    }
    MM(aE, bE);

    // kk1
    LDA(aE, Ac, 2); LDB(bE, Bc, 2);
    if (pf) {
      gl_lds16(gAs + kb + 3 * rj8,  An + sAo + 3072);
      gl_lds16(gAs + kb + 4 * rj8,  An + sAo + 4096);
      gl_lds16(gAs + kb + 5 * rj8,  An + sAo + 5120);
      gl_lds16(gBs + kb + 2 * rj8,  Bn + sBo + 2048);
      gl_lds16(gBs + kb + 3 * rj8,  Bn + sBo + 3072);
    }
    MM(aO, bO);

    // kk2
    LDA(aO, Ac, 3); LDB(bO, Bc, 3);
    if (pf) {
      gl_lds16(gAs + kb + 6 * rj8,  An + sAo + 6144);
      gl_lds16(gAs + kb + 7 * rj8,  An + sAo + 7168);
      if constexpr (NBS == 8) {
        gl_lds16(gBs + kb + 4 * rj8, Bn + sBo + 4096);
        gl_lds16(gBs + kb + 5 * rj8, Bn + sBo + 5120);
        gl_lds16(gBs + kb + 6 * rj8, Bn + sBo + 6144);
        gl_lds16(gBs + kb + 7 * rj8, Bn + sBo + 7168);
      }
    }
    MM(aE, bE);

    // kk3: MFMA first (builds pipe backlog), then wait+barrier, then next reads
    MM(aO, bO);
    if (pf) {
      WAITV0();       // stages issued 1.5-3 k-steps ago -> complete; per-wave
      SBAR();         // ... and barrier makes it block-wide proof
      LDA(aE, An, 0); LDB(bE, Bn, 0);
    }
    kb += 128;
  }

  // ---------- epilogue (32x32 C layout: col=lane&31, row=r+8g+4*(lane>>5)) ----
  const int ccol = lane & 31;
  const int rh   = (lane >> 5) << 2;
  const bool isz = (EPI == 0) && (n0 >= (size_t)D_INNER);
#pragma unroll
  for (int mi = 0; mi < 4; ++mi) {
#pragma unroll
    for (int ni = 0; ni < NF; ++ni) {
#pragma unroll
      for (int g = 0; g < 4; ++g) {
#pragma unroll
        for (int r = 0; r < 4; ++r) {
          const float v = acc[mi][ni][g * 4 + r];
          const size_t row = m0 + (size_t)(widm * 128 + mi * 32 + g * 8 + r + rh);
          const size_t col = n0 + (size_t)(widn * (BN / 2) + ni * 32 + ccol);
          if (EPI == 0) {
            if (!isz) ob0[row * D_INNER + col] = f2bf(v);
            else      ob1[row * D_INNER + (col - D_INNER)] = f2bf(siluf_(v));
          } else if (EPI == 1) {
            ob0[row * (size_t)N + col] = f2bf(v);
          } else {
            of[row * (size_t)N + col] = v + ef[row * (size_t)N + col];
          }
        }
      }
    }
  }
}

// ---------------- causal depthwise conv (K=4) + SiLU ----------------
__global__ void __launch_bounds__(256)
conv_silu_kernel(const u16* __restrict__ xin, const float* __restrict__ cw,
                 const float* __restrict__ cb, u16* __restrict__ xc) {
  const int c   = blockIdx.x * 256 + threadIdx.x;
  const int l0  = blockIdx.y * 8;
  const int bat = blockIdx.z;
  const size_t base = ((size_t)bat * LSEQ) * D_INNER + c;
  const float w0 = cw[c * 4 + 0], w1 = cw[c * 4 + 1], w2 = cw[c * 4 + 2], w3 = cw[c * 4 + 3];
  const float bb = cb[c];
  float v[11];
#pragma unroll
  for (int i = 0; i < 11; ++i) {
    const int l = l0 - 3 + i;
    v[i] = (l >= 0) ? bf2f(xin[base + (size_t)l * D_INNER]) : 0.0f;
  }
#pragma unroll
  for (int r = 0; r < 8; ++r) {
    const float acc = bb + w0 * v[r] + w1 * v[r + 1] + w2 * v[r + 2] + w3 * v[r + 3];
    xc[base + (size_t)(l0 + r) * D_INNER] = f2bf(siluf_(acc));
  }
}

// ---------------- chunked scan: pass A (2 channels/thread) ----------------
__global__ void __launch_bounds__(256)
scan_a_kernel(const u16* __restrict__ g, const u16* __restrict__ xc,
              const float* __restrict__ gbias,
              float* __restrict__ cA, float* __restrict__ cB) {
  const int c   = (blockIdx.x * 256 + threadIdx.x) * 2;
  const int ch  = blockIdx.y;
  const int bat = blockIdx.z;
  const float bb0 = gbias[c], bb1 = gbias[c + 1];
  size_t idx = ((size_t)bat * LSEQ + (size_t)ch * CHUNK) * D_INNER + c;
  float pA0 = 1.0f, hB0 = 0.0f, pA1 = 1.0f, hB1 = 0.0f;
  for (int t = 0; t < CHUNK; ++t) {
    const ushort2 gg = *(const ushort2*)(g + idx);
    const ushort2 xx = *(const ushort2*)(xc + idx);
    const float a0 = sigmoidf_(bf2f(gg.x) + bb0);
    const float a1 = sigmoidf_(bf2f(gg.y) + bb1);
    pA0 *= a0; hB0 = a0 * hB0 + (1.0f - a0) * bf2f(xx.x);
    pA1 *= a1; hB1 = a1 * hB1 + (1.0f - a1) * bf2f(xx.y);
    idx += D_INNER;
  }
  const size_t o = ((size_t)bat * NCHUNK + ch) * D_INNER + c;
  *(float2*)(cA + o) = make_float2(pA0, pA1);
  *(float2*)(cB + o) = make_float2(hB0, hB1);
}

// ---------------- pass B: serial scan over chunk summaries ----------------
__global__ void __launch_bounds__(256)
scan_b_kernel(const float* __restrict__ cA, const float* __restrict__ cB,
              float* __restrict__ carry) {
  const int tid = blockIdx.x * 256 + threadIdx.x;  // BATCH*D_INNER = 4096
  const int bat = tid >> 11;
  const int c   = tid & (D_INNER - 1);
  float h = 0.0f;
  const size_t base = (size_t)bat * NCHUNK * D_INNER + c;
  for (int i = 0; i < NCHUNK; ++i) {
    const size_t o = base + (size_t)i * D_INNER;
    carry[o] = h;
    h = cA[o] * h + cB[o];
  }
}

// ---------------- pass C: apply carry, gate by silu(z), -> bf16 ----------------
__global__ void __launch_bounds__(256)
scan_c_kernel(const u16* __restrict__ g, const u16* __restrict__ xc,
              const u16* __restrict__ sz, const float* __restrict__ gbias,
              const float* __restrict__ carry, u16* __restrict__ yg) {
  const int c   = (blockIdx.x * 256 + threadIdx.x) * 2;
  const int ch  = blockIdx.y;
  const int bat = blockIdx.z;
  const float bb0 = gbias[c], bb1 = gbias[c + 1];
  const float2 h2 = *(const float2*)(carry + ((size_t)bat * NCHUNK + ch) * D_INNER + c);
  float h0 = h2.x, h1 = h2.y;
  size_t idx = ((size_t)bat * LSEQ + (size_t)ch * CHUNK) * D_INNER + c;
  for (int t = 0; t < CHUNK; ++t) {
    const ushort2 gg = *(const ushort2*)(g + idx);
    const ushort2 xx = *(const ushort2*)(xc + idx);
    const ushort2 zz = *(const ushort2*)(sz + idx);
    const float a0 = sigmoidf_(bf2f(gg.x) + bb0);
    const float a1 = sigmoidf_(bf2f(gg.y) + bb1);
    h0 = a0 * h0 + (1.0f - a0) * bf2f(xx.x);
    h1 = a1 * h1 + (1.0f - a1) * bf2f(xx.y);
    ushort2 o2;
    o2.x = f2bf(h0 * bf2f(zz.x));
    o2.y = f2bf(h1 * bf2f(zz.y));
    *(ushort2*)(yg + idx) = o2;
    idx += D_INNER;
  }
}

extern "C" void kernel_launch(void* const* d_in, const int* in_sizes, int n_in,
                              void* d_out, int out_size, void* d_ws, size_t ws_size,
                              hipStream_t stream) {
  const float* x         = (const float*)d_in[0];
  const float* norm_w    = (const float*)d_in[1];
  const float* norm_b    = (const float*)d_in[2];
  const float* in_proj_w = (const float*)d_in[3];
  const float* conv_w    = (const float*)d_in[4];
  const float* conv_b    = (const float*)d_in[5];
  const float* gate_w    = (const float*)d_in[6];
  const float* gate_b    = (const float*)d_in[7];
  const float* out_proj_w= (const float*)d_in[8];
  float* out = (float*)d_out;

  char* p = (char*)d_ws;
  u16* xn      = (u16*)p; p += (size_t)M_ROWS * D_MODEL * 2;
  u16* w_in    = (u16*)p; p += (size_t)2 * D_INNER * D_MODEL * 2;
  u16* w_gate  = (u16*)p; p += (size_t)D_INNER * D_INNER * 2;
  u16* w_out   = (u16*)p; p += (size_t)D_MODEL * D_INNER * 2;
  u16* x_inner = (u16*)p; p += (size_t)M_ROWS * D_INNER * 2;
  u16* szb     = (u16*)p; p += (size_t)M_ROWS * D_INNER * 2;
  u16* xconv   = (u16*)p; p += (size_t)M_ROWS * D_INNER * 2;
  u16* gbuf    = (u16*)p; p += (size_t)M_ROWS * D_INNER * 2;   // raw GEMM2 out (pre-sigmoid)
  u16* yg      = (u16*)p; p += (size_t)M_ROWS * D_INNER * 2;
  float* cA    = (float*)p; p += (size_t)BATCH * NCHUNK * D_INNER * 4;
  float* cB    = (float*)p; p += (size_t)BATCH * NCHUNK * D_INNER * 4;
  float* carry = (float*)p; p += (size_t)BATCH * NCHUNK * D_INNER * 4;
  if ((size_t)(p - (char*)d_ws) > ws_size) return;

  cast_bf16_kernel<<<dim3(2 * D_INNER * D_MODEL / 4 / 256), 256, 0, stream>>>(in_proj_w, w_in, 2 * D_INNER * D_MODEL / 4);
  cast_bf16_kernel<<<dim3(D_INNER * D_INNER / 4 / 256), 256, 0, stream>>>(gate_w, w_gate, D_INNER * D_INNER / 4);
  cast_bf16_kernel<<<dim3(D_MODEL * D_INNER / 4 / 256), 256, 0, stream>>>(out_proj_w, w_out, D_MODEL * D_INNER / 4);

  ln_kernel<<<dim3(M_ROWS), 256, 0, stream>>>(x, norm_w, norm_b, xn);

  gemmW<0, 256><<<dim3((M_ROWS / 256) * (2 * D_INNER / 256)), 256, 0, stream>>>(
      xn, w_in, M_ROWS, 2 * D_INNER, D_MODEL, nullptr, nullptr, x_inner, szb);

  conv_silu_kernel<<<dim3(D_INNER / 256, LSEQ / 8, BATCH), 256, 0, stream>>>(x_inner, conv_w, conv_b, xconv);

  gemmW<1, 256><<<dim3((M_ROWS / 256) * (D_INNER / 256)), 256, 0, stream>>>(
      xconv, w_gate, M_ROWS, D_INNER, D_INNER, nullptr, nullptr, gbuf, nullptr);

  scan_a_kernel<<<dim3(D_INNER / 512, NCHUNK, BATCH), 256, 0, stream>>>(gbuf, xconv, gate_b, cA, cB);
  scan_b_kernel<<<dim3(BATCH * D_INNER / 256), 256, 0, stream>>>(cA, cB, carry);
  scan_c_kernel<<<dim3(D_INNER / 512, NCHUNK, BATCH), 256, 0, stream>>>(gbuf, xconv, szb, gate_b, carry, yg);

  gemmW<2, 128><<<dim3((M_ROWS / 256) * (D_MODEL / 128)), 256, 0, stream>>>(
      yg, w_out, M_ROWS, D_MODEL, D_INNER, x, out, nullptr, nullptr);
}

// Round 7
// 362.879 us; speedup vs baseline: 1.0739x; 1.0739x over previous
//
#include <hip/hip_runtime.h>
#include <cstdint>

#define D_MODEL 1024
#define D_INNER 2048
#define LSEQ    4096
#define BATCH   2
#define M_ROWS  (BATCH * LSEQ)   // 8192
#define CHUNK   128
#define NCHUNK  (LSEQ / CHUNK)   // 32

typedef unsigned short u16;
typedef __bf16 bf16x8 __attribute__((ext_vector_type(8)));
typedef float f32x4 __attribute__((ext_vector_type(4)));
typedef u16 u16x4 __attribute__((ext_vector_type(4)));

__device__ __forceinline__ u16 f2bf(float f) {
  union { float f; unsigned u; } x; x.f = f;
  unsigned u = x.u;
  unsigned r = (u + 0x7FFFu + ((u >> 16) & 1u)) >> 16;
  return (u16)r;
}
__device__ __forceinline__ float bf2f(u16 h) {
  union { unsigned u; float f; } x; x.u = ((unsigned)h) << 16;
  return x.f;
}
__device__ __forceinline__ float sigmoidf_(float v) { return 1.0f / (1.0f + expf(-v)); }
__device__ __forceinline__ float siluf_(float v)    { return v / (1.0f + expf(-v)); }

__device__ __forceinline__ void gl_lds16(const void* g, void* l) {
  __builtin_amdgcn_global_load_lds(
      (const __attribute__((address_space(1))) void*)g,
      (__attribute__((address_space(3))) void*)l, 16, 0, 0);
}

#define SBAR()   asm volatile("s_barrier" ::: "memory")
#define WAITV0() asm volatile("s_waitcnt vmcnt(0)" ::: "memory")
#define WAITV4() asm volatile("s_waitcnt vmcnt(4)" ::: "memory")

// ---------------- cast fp32 -> bf16 (vectorized) ----------------
__global__ void __launch_bounds__(256)
cast_bf16_kernel(const float* __restrict__ in, u16* __restrict__ out, int n4) {
  int i = blockIdx.x * 256 + threadIdx.x;
  if (i < n4) {
    float4 v = ((const float4*)in)[i];
    u16x4 o;
    o.x = f2bf(v.x); o.y = f2bf(v.y); o.z = f2bf(v.z); o.w = f2bf(v.w);
    ((u16x4*)out)[i] = o;
  }
}

// ---------------- LayerNorm -> bf16 ----------------
__global__ void __launch_bounds__(256)
ln_kernel(const float* __restrict__ x, const float* __restrict__ w,
          const float* __restrict__ b, u16* __restrict__ xn) {
  const int row = blockIdx.x;
  const int t = threadIdx.x;
  const float4 v = ((const float4*)(x + (size_t)row * D_MODEL))[t];
  float s  = v.x + v.y + v.z + v.w;
  float ss = v.x * v.x + v.y * v.y + v.z * v.z + v.w * v.w;
#pragma unroll
  for (int o = 32; o > 0; o >>= 1) {
    s  += __shfl_xor(s, o);
    ss += __shfl_xor(ss, o);
  }
  __shared__ float red[8];
  const int wid = t >> 6, lane = t & 63;
  if (lane == 0) { red[wid] = s; red[4 + wid] = ss; }
  __syncthreads();
  s  = red[0] + red[1] + red[2] + red[3];
  ss = red[4] + red[5] + red[6] + red[7];
  const float mu  = s * (1.0f / D_MODEL);
  const float var = ss * (1.0f / D_MODEL) - mu * mu;
  const float rs  = rsqrtf(var + 1e-5f);
  const float4 wv = ((const float4*)w)[t];
  const float4 bv = ((const float4*)b)[t];
  u16x4 o4;
  o4.x = f2bf((v.x - mu) * rs * wv.x + bv.x);
  o4.y = f2bf((v.y - mu) * rs * wv.y + bv.y);
  o4.z = f2bf((v.z - mu) * rs * wv.z + bv.z);
  o4.w = f2bf((v.w - mu) * rs * wv.w + bv.w);
  ((u16x4*)(xn + (size_t)row * D_MODEL))[t] = o4;
}

// ======== 128x128 BK=64 4-wave dbuf GEMM, 2 blocks/CU, C = A * B^T ========
// LDS 64KB: [buf][A 2halves x 128rows x 64B][B same]. Counted-vmcnt ledger:
// per tile P1 issues the 4 kk0-half loads(t+1), P2 the 4 kk1-half loads(t+1);
// each wait is vmcnt(4) proving the group issued one full phase earlier;
// steady-state in-flight never drops below 4 (T4). Cross-block TLP (2/CU)
// covers per-block stalls (m97/m114 mechanism). Swizzle: slot q^((row>>1)&3)
// via pre-swizzled global source + swizzled ds_read (0-conflict pattern).
#define MFMA_BF16 __builtin_amdgcn_mfma_f32_16x16x32_bf16

template<int EPI>
__global__ void __launch_bounds__(256, 2)
gemm128(const u16* __restrict__ A, const u16* __restrict__ Bm,
        int M, int N, int K,
        const float* __restrict__ ef, float* __restrict__ of,
        u16* __restrict__ ob0, u16* __restrict__ ob1) {
  __shared__ __align__(1024) char lds[65536];
  const int tid  = threadIdx.x;
  const int wid  = tid >> 6, lane = tid & 63;
  const int nbx  = N >> 7;
  const int nwg  = nbx * (M >> 7);
  const int bid  = blockIdx.x;
  const int cpx  = nwg >> 3;                      // nwg % 8 == 0 for all our shapes
  const int swzb = (bid & 7) * cpx + (bid >> 3);  // XCD-aware swizzle
  const int bx   = swzb % nbx, by = swzb / nbx;
  const size_t m0 = (size_t)by << 7, n0 = (size_t)bx << 7;
  const int wr = wid >> 1, wc = wid & 1;          // 2x2 wave grid; wave tile 64x64
  const size_t rb = (size_t)K * 2;

  // ---- staging: per-lane pre-swizzled global source, linear LDS dest ----
  // lane covers (row = wid*16 + lane>>2, slot s = lane&3); content of LDS
  // slot (row,s) = global 16B chunk (s ^ ((row>>1)&3)); (row>>1)&3 == (lane>>3)&3.
  const int sslot = (((lane & 3) ^ ((lane >> 3) & 3)) << 4);
  const char* gA = (const char*)A  + (m0 + (size_t)(wid * 16 + (lane >> 2))) * rb + sslot;
  const char* gB = (const char*)Bm + (n0 + (size_t)(wid * 16 + (lane >> 2))) * rb + sslot;
  const int sd = wid * 1024;   // wave slice within a 64-row stage chunk

  // ---- fragment reads: byte = kk*8192 + row*64 + ((q ^ ((row>>1)&3))<<4) ----
  const int q = lane >> 4, r15 = lane & 15;
  const int xr = ((q ^ ((r15 >> 1) & 3)) << 4);
  const int aoff = (wr * 64 + r15) * 64 + xr;     // + mi*1024 + kk*8192
  const int boff = (wc * 64 + r15) * 64 + xr;     // + ni*1024 + kk*8192 (base +16384)

  f32x4 acc[4][4] = {};
  const int nk = K >> 6;

  auto STG = [&](const char* g, char* ldsbase, int kk, int r0, size_t kbv) {
    gl_lds16(g + kbv + kk * 64 + (size_t)r0 * rb, ldsbase + kk * 8192 + r0 * 64 + sd);
  };

  // ---- prologue: stage tile 0 (kk0 group then kk1 group); prove kk0 ----
  STG(gA, lds, 0, 0, 0); STG(gA, lds, 0, 64, 0);
  STG(gB, lds + 16384, 0, 0, 0); STG(gB, lds + 16384, 0, 64, 0);
  STG(gA, lds, 1, 0, 0); STG(gA, lds, 1, 64, 0);
  STG(gB, lds + 16384, 1, 0, 0); STG(gB, lds + 16384, 1, 64, 0);
  WAITV4();      // kk0 group done; kk1 group (4) stays in flight
  SBAR();

  size_t kb = 128;
  for (int t = 0; t < nk; ++t) {
    const int cur = t & 1;
    const char* Ac = lds + cur * 32768;
    const char* Bc = Ac + 16384;
    char* An = lds + ((cur ^ 1) * 32768);
    char* Bn = An + 16384;
    const bool pf = (t + 1 < nk);
    bf16x8 af[4], bf[4];

    // ---- P1: issue kk0(t+1); read kk0(t); MFMA; vmcnt(4) proves kk1(t) ----
    if (pf) {
      STG(gA, An, 0, 0, kb); STG(gA, An, 0, 64, kb);
      STG(gB, Bn, 0, 0, kb); STG(gB, Bn, 0, 64, kb);
    }
#pragma unroll
    for (int mi = 0; mi < 4; ++mi) af[mi] = *(const bf16x8*)(Ac + aoff + mi * 1024);
#pragma unroll
    for (int ni = 0; ni < 4; ++ni) bf[ni] = *(const bf16x8*)(Bc + boff + ni * 1024);
    __builtin_amdgcn_s_setprio(1);
#pragma unroll
    for (int mi = 0; mi < 4; ++mi)
#pragma unroll
      for (int ni = 0; ni < 4; ++ni)
        acc[mi][ni] = MFMA_BF16(af[mi], bf[ni], acc[mi][ni], 0, 0, 0);
    __builtin_amdgcn_s_setprio(0);
    if (pf) { WAITV4(); } else { WAITV0(); }
    SBAR();

    // ---- P2: issue kk1(t+1); read kk1(t); MFMA; vmcnt(4) proves kk0(t+1) ----
    if (pf) {
      STG(gA, An, 1, 0, kb); STG(gA, An, 1, 64, kb);
      STG(gB, Bn, 1, 0, kb); STG(gB, Bn, 1, 64, kb);
    }
#pragma unroll
    for (int mi = 0; mi < 4; ++mi) af[mi] = *(const bf16x8*)(Ac + 8192 + aoff + mi * 1024);
#pragma unroll
    for (int ni = 0; ni < 4; ++ni) bf[ni] = *(const bf16x8*)(Bc + 8192 + boff + ni * 1024);
    __builtin_amdgcn_s_setprio(1);
#pragma unroll
    for (int mi = 0; mi < 4; ++mi)
#pragma unroll
      for (int ni = 0; ni < 4; ++ni)
        acc[mi][ni] = MFMA_BF16(af[mi], bf[ni], acc[mi][ni], 0, 0, 0);
    __builtin_amdgcn_s_setprio(0);
    if (pf) { WAITV4(); SBAR(); }
    kb += 128;
  }

  // ---------- epilogue (16x16 C layout: col=lane&15, row=(lane>>4)*4+r) ----
  const int c0 = lane & 15;
  const int r0 = (lane >> 4) << 2;
  const bool isz = (EPI == 0) && (n0 >= (size_t)D_INNER);
#pragma unroll
  for (int mi = 0; mi < 4; ++mi) {
#pragma unroll
    for (int ni = 0; ni < 4; ++ni) {
#pragma unroll
      for (int rg = 0; rg < 4; ++rg) {
        const size_t row = m0 + (size_t)(wr * 64 + mi * 16 + r0 + rg);
        const size_t col = n0 + (size_t)(wc * 64 + ni * 16 + c0);
        const float v = acc[mi][ni][rg];
        if (EPI == 0) {
          if (!isz) ob0[row * D_INNER + col] = f2bf(v);
          else      ob1[row * D_INNER + (col - D_INNER)] = f2bf(siluf_(v));
        } else if (EPI == 1) {
          ob0[row * (size_t)N + col] = f2bf(v);
        } else {
          of[row * (size_t)N + col] = v + ef[row * (size_t)N + col];
        }
      }
    }
  }
}

// ---------------- causal depthwise conv (K=4) + SiLU ----------------
__global__ void __launch_bounds__(256)
conv_silu_kernel(const u16* __restrict__ xin, const float* __restrict__ cw,
                 const float* __restrict__ cb, u16* __restrict__ xc) {
  const int c   = blockIdx.x * 256 + threadIdx.x;
  const int l0  = blockIdx.y * 8;
  const int bat = blockIdx.z;
  const size_t base = ((size_t)bat * LSEQ) * D_INNER + c;
  const float w0 = cw[c * 4 + 0], w1 = cw[c * 4 + 1], w2 = cw[c * 4 + 2], w3 = cw[c * 4 + 3];
  const float bb = cb[c];
  float v[11];
#pragma unroll
  for (int i = 0; i < 11; ++i) {
    const int l = l0 - 3 + i;
    v[i] = (l >= 0) ? bf2f(xin[base + (size_t)l * D_INNER]) : 0.0f;
  }
#pragma unroll
  for (int r = 0; r < 8; ++r) {
    const float acc = bb + w0 * v[r] + w1 * v[r + 1] + w2 * v[r + 2] + w3 * v[r + 3];
    xc[base + (size_t)(l0 + r) * D_INNER] = f2bf(siluf_(acc));
  }
}

// ---------------- chunked scan: pass A (2 channels/thread) ----------------
__global__ void __launch_bounds__(256)
scan_a_kernel(const u16* __restrict__ g, const u16* __restrict__ xc,
              const float* __restrict__ gbias,
              float* __restrict__ cA, float* __restrict__ cB) {
  const int c   = (blockIdx.x * 256 + threadIdx.x) * 2;
  const int ch  = blockIdx.y;
  const int bat = blockIdx.z;
  const float bb0 = gbias[c], bb1 = gbias[c + 1];
  size_t idx = ((size_t)bat * LSEQ + (size_t)ch * CHUNK) * D_INNER + c;
  float pA0 = 1.0f, hB0 = 0.0f, pA1 = 1.0f, hB1 = 0.0f;
  for (int t = 0; t < CHUNK; ++t) {
    const ushort2 gg = *(const ushort2*)(g + idx);
    const ushort2 xx = *(const ushort2*)(xc + idx);
    const float a0 = sigmoidf_(bf2f(gg.x) + bb0);
    const float a1 = sigmoidf_(bf2f(gg.y) + bb1);
    pA0 *= a0; hB0 = a0 * hB0 + (1.0f - a0) * bf2f(xx.x);
    pA1 *= a1; hB1 = a1 * hB1 + (1.0f - a1) * bf2f(xx.y);
    idx += D_INNER;
  }
  const size_t o = ((size_t)bat * NCHUNK + ch) * D_INNER + c;
  *(float2*)(cA + o) = make_float2(pA0, pA1);
  *(float2*)(cB + o) = make_float2(hB0, hB1);
}

// ---------------- pass B: serial scan over chunk summaries ----------------
__global__ void __launch_bounds__(256)
scan_b_kernel(const float* __restrict__ cA, const float* __restrict__ cB,
              float* __restrict__ carry) {
  const int tid = blockIdx.x * 256 + threadIdx.x;  // BATCH*D_INNER = 4096
  const int bat = tid >> 11;
  const int c   = tid & (D_INNER - 1);
  float h = 0.0f;
  const size_t base = (size_t)bat * NCHUNK * D_INNER + c;
  for (int i = 0; i < NCHUNK; ++i) {
    const size_t o = base + (size_t)i * D_INNER;
    carry[o] = h;
    h = cA[o] * h + cB[o];
  }
}

// ---------------- pass C: apply carry, gate by silu(z), -> bf16 ----------------
__global__ void __launch_bounds__(256)
scan_c_kernel(const u16* __restrict__ g, const u16* __restrict__ xc,
              const u16* __restrict__ sz, const float* __restrict__ gbias,
              const float* __restrict__ carry, u16* __restrict__ yg) {
  const int c   = (blockIdx.x * 256 + threadIdx.x) * 2;
  const int ch  = blockIdx.y;
  const int bat = blockIdx.z;
  const float bb0 = gbias[c], bb1 = gbias[c + 1];
  const float2 h2 = *(const float2*)(carry + ((size_t)bat * NCHUNK + ch) * D_INNER + c);
  float h0 = h2.x, h1 = h2.y;
  size_t idx = ((size_t)bat * LSEQ + (size_t)ch * CHUNK) * D_INNER + c;
  for (int t = 0; t < CHUNK; ++t) {
    const ushort2 gg = *(const ushort2*)(g + idx);
    const ushort2 xx = *(const ushort2*)(xc + idx);
    const ushort2 zz = *(const ushort2*)(sz + idx);
    const float a0 = sigmoidf_(bf2f(gg.x) + bb0);
    const float a1 = sigmoidf_(bf2f(gg.y) + bb1);
    h0 = a0 * h0 + (1.0f - a0) * bf2f(xx.x);
    h1 = a1 * h1 + (1.0f - a1) * bf2f(xx.y);
    ushort2 o2;
    o2.x = f2bf(h0 * bf2f(zz.x));
    o2.y = f2bf(h1 * bf2f(zz.y));
    *(ushort2*)(yg + idx) = o2;
    idx += D_INNER;
  }
}

extern "C" void kernel_launch(void* const* d_in, const int* in_sizes, int n_in,
                              void* d_out, int out_size, void* d_ws, size_t ws_size,
                              hipStream_t stream) {
  const float* x         = (const float*)d_in[0];
  const float* norm_w    = (const float*)d_in[1];
  const float* norm_b    = (const float*)d_in[2];
  const float* in_proj_w = (const float*)d_in[3];
  const float* conv_w    = (const float*)d_in[4];
  const float* conv_b    = (const float*)d_in[5];
  const float* gate_w    = (const float*)d_in[6];
  const float* gate_b    = (const float*)d_in[7];
  const float* out_proj_w= (const float*)d_in[8];
  float* out = (float*)d_out;

  char* p = (char*)d_ws;
  u16* xn      = (u16*)p; p += (size_t)M_ROWS * D_MODEL * 2;
  u16* w_in    = (u16*)p; p += (size_t)2 * D_INNER * D_MODEL * 2;
  u16* w_gate  = (u16*)p; p += (size_t)D_INNER * D_INNER * 2;
  u16* w_out   = (u16*)p; p += (size_t)D_MODEL * D_INNER * 2;
  u16* x_inner = (u16*)p; p += (size_t)M_ROWS * D_INNER * 2;
  u16* szb     = (u16*)p; p += (size_t)M_ROWS * D_INNER * 2;
  u16* xconv   = (u16*)p; p += (size_t)M_ROWS * D_INNER * 2;
  u16* gbuf    = (u16*)p; p += (size_t)M_ROWS * D_INNER * 2;   // raw GEMM2 out (pre-sigmoid)
  u16* yg      = (u16*)p; p += (size_t)M_ROWS * D_INNER * 2;
  float* cA    = (float*)p; p += (size_t)BATCH * NCHUNK * D_INNER * 4;
  float* cB    = (float*)p; p += (size_t)BATCH * NCHUNK * D_INNER * 4;
  float* carry = (float*)p; p += (size_t)BATCH * NCHUNK * D_INNER * 4;
  if ((size_t)(p - (char*)d_ws) > ws_size) return;

  cast_bf16_kernel<<<dim3(2 * D_INNER * D_MODEL / 4 / 256), 256, 0, stream>>>(in_proj_w, w_in, 2 * D_INNER * D_MODEL / 4);
  cast_bf16_kernel<<<dim3(D_INNER * D_INNER / 4 / 256), 256, 0, stream>>>(gate_w, w_gate, D_INNER * D_INNER / 4);
  cast_bf16_kernel<<<dim3(D_MODEL * D_INNER / 4 / 256), 256, 0, stream>>>(out_proj_w, w_out, D_MODEL * D_INNER / 4);

  ln_kernel<<<dim3(M_ROWS), 256, 0, stream>>>(x, norm_w, norm_b, xn);

  gemm128<0><<<dim3((M_ROWS / 128) * (2 * D_INNER / 128)), 256, 0, stream>>>(
      xn, w_in, M_ROWS, 2 * D_INNER, D_MODEL, nullptr, nullptr, x_inner, szb);

  conv_silu_kernel<<<dim3(D_INNER / 256, LSEQ / 8, BATCH), 256, 0, stream>>>(x_inner, conv_w, conv_b, xconv);

  gemm128<1><<<dim3((M_ROWS / 128) * (D_INNER / 128)), 256, 0, stream>>>(
      xconv, w_gate, M_ROWS, D_INNER, D_INNER, nullptr, nullptr, gbuf, nullptr);

  scan_a_kernel<<<dim3(D_INNER / 512, NCHUNK, BATCH), 256, 0, stream>>>(gbuf, xconv, gate_b, cA, cB);
  scan_b_kernel<<<dim3(BATCH * D_INNER / 256), 256, 0, stream>>>(cA, cB, carry);
  scan_c_kernel<<<dim3(D_INNER / 512, NCHUNK, BATCH), 256, 0, stream>>>(gbuf, xconv, szb, gate_b, carry, yg);

  gemm128<2><<<dim3((M_ROWS / 128) * (D_MODEL / 128)), 256, 0, stream>>>(
      yg, w_out, M_ROWS, D_MODEL, D_INNER, x, out, nullptr, nullptr);
}